// Round 8
// baseline (105.423 us; speedup 1.0000x reference)
//
#include <hip/hip_runtime.h>
#include <hip/hip_bf16.h>

// CustomBernsteinLayer: out[b,o] = sum_{i,k} ber[b,i,k] * (coeffs[o,i,k]*weights[o,i])
// ber = (1+t)^k (1-t)^(8-k), t = tanh(x).  With e = exp2(2x*log2e):
//   (1-t) = 2/(e+1) = q, ratio r = e, p0 = q^8, ber_{k+1} = ber_k * r.
// bf16 MFMA GEMM M=16384 N=256 K=2304, per-lane in-register A-gen (validated).
// Round 8:
//  - gemm: ROLLED main loop (12 groups x 3 steps, #pragma unroll 1) -> ~3 KB
//    I$-resident body instead of ~25 KB streamed cold (the common factor in
//    all flat ~40us variants). Groups of 3 align with the 9-step chunks; x
//    prefetched into xb[] 1.5 groups ahead of the SETUP that consumes it.
//  - prep: one o per block, coalesced coeff reads through LDS (old prep read
//    36B-strided / 9KB-apart -> ~512 txns/wave; it was ~half the non-fill time).

#define BDIM 16384
#define IDIM 256
#define ODIM 256
#define NK 9
#define NSTEP 36
#define STEP_ELEMS (ODIM * 64)   // 16384 bf16 (32 KB) per K-step block
#define GSTEP 3                  // K-steps per staged group
#define NGROUP 12                // NSTEP / GSTEP

typedef short short8 __attribute__((ext_vector_type(8)));
typedef float floatx4 __attribute__((ext_vector_type(4)));

// ---------------------------------------------------------------------------
// prep_wc3: wc[step][e] = bf16(coeffs[o,i,k]*weights[o,i]) in fragment-ready
// layout e = (((o>>4)*2+s)*64 + (o&15) + quad*16)*8 + j, il = s*32+quad*8+j,
// step = (i>>6)*9 + k.  One o per block: coeffs row (2304 floats) loaded
// fully coalesced into LDS, then per-thread (i=t) gather at stride 9
// (gcd(9,32)=1 -> conflict-free) and 9 bf16 stores in the validated layout.
// ---------------------------------------------------------------------------
__global__ __launch_bounds__(256) void prep_wc3(const float* __restrict__ weights,
                                                const float* __restrict__ coeffs,
                                                ushort* __restrict__ wc) {
    __shared__ float cl[IDIM * NK];          // 9216 B
    const int o = blockIdx.x;
    const int t = threadIdx.x;
    const float* cb = coeffs + (size_t)o * (IDIM * NK);
#pragma unroll
    for (int j = 0; j < NK; ++j)
        cl[t + 256 * j] = cb[t + 256 * j];   // coalesced sweep
    __syncthreads();

    const float wv = weights[o * IDIM + t];
    const int ic = t >> 6, il = t & 63;
    const int s = il >> 5, quad = (il >> 3) & 3, j = il & 7;
    const size_t base = (size_t)((((o >> 4) * 2 + s) * 64) + (o & 15) + quad * 16) * 8 + j;
    ushort* wb = wc + base;
#pragma unroll
    for (int k = 0; k < NK; ++k) {
        __hip_bfloat16 b = __float2bfloat16(cl[t * NK + k] * wv);
        wb[(size_t)(ic * NK + k) * STEP_ELEMS] = *(ushort*)&b;
    }
}

// ---------------------------------------------------------------------------
// GEMM: 256 blocks x 512 threads (8 waves), 1 block/CU.
//   cg = blk & 3  -> cols cg*64 .. +63 (whole block)
//   rg = blk >> 2 -> wave w: rows rg*256 + w*32 .. +31
// Per-lane A state: rows rb + m*16 + (lane&15), m in {0,1};
//   i_local = s*32 + (lane>>4)*8 + j.
// B: 3-step groups (24 KB cg-slice) double-buffered in 48 KB LDS via
// global_load_lds width 16, staged one group ahead of the consuming barrier.
// Rolled group loop; fragment (n,s) of in-group step q at
// Blds[buf][q*4096 + (n*2+s)*512 + lane*8] (stride-1, conflict-free b128).
// ---------------------------------------------------------------------------
__global__ __launch_bounds__(512, 2) void bern_gemm(const float* __restrict__ x,
                                                    const ushort* __restrict__ wc,
                                                    float* __restrict__ out) {
    __shared__ ushort Blds[2][GSTEP * 4096];   // 2 x 24 KB

    const int tid  = threadIdx.x;
    const int wave = tid >> 6;
    const int lane = tid & 63;
    const int cg   = blockIdx.x & 3;
    const int rb   = (blockIdx.x >> 2) * 256 + wave * 32;
    const int lrow = lane & 15;
    const int jseg = (lane >> 4) * 8;      // 0,8,16,24

    float p[2][2][8];   // [m][s][j] running Bernstein value
    float r[2][2][8];   // ratio e = exp2(2x log2 e)
    float xb[2][2][8];  // prefetched raw x for the next chunk
    floatx4 acc[2][4];
    floatx4 zero = {0.0f, 0.0f, 0.0f, 0.0f};
#pragma unroll
    for (int m = 0; m < 2; ++m)
#pragma unroll
        for (int n = 0; n < 4; ++n)
            acc[m][n] = zero;

#define LOAD_X(ic_)                                                             \
    {                                                                           \
        _Pragma("unroll") for (int m = 0; m < 2; ++m)                           \
        _Pragma("unroll") for (int s = 0; s < 2; ++s) {                         \
            const float* xp = x + (size_t)(rb + m * 16 + lrow) * IDIM           \
                              + (ic_) * 64 + s * 32 + jseg;                     \
            float4 v0 = *(const float4*)(xp);                                   \
            float4 v1 = *(const float4*)(xp + 4);                               \
            xb[m][s][0] = v0.x; xb[m][s][1] = v0.y;                             \
            xb[m][s][2] = v0.z; xb[m][s][3] = v0.w;                             \
            xb[m][s][4] = v1.x; xb[m][s][5] = v1.y;                             \
            xb[m][s][6] = v1.z; xb[m][s][7] = v1.w;                             \
        }                                                                       \
    }

#define SETUP_BASIS()                                                           \
    {                                                                           \
        _Pragma("unroll") for (int m = 0; m < 2; ++m)                           \
        _Pragma("unroll") for (int s = 0; s < 2; ++s)                           \
        _Pragma("unroll") for (int e = 0; e < 8; ++e) {                         \
            float t  = __builtin_amdgcn_exp2f(xb[m][s][e] * 2.8853900817779268f);\
            float q  = 2.0f * __builtin_amdgcn_rcpf(t + 1.0f);                  \
            float q2 = q * q;                                                   \
            float q4 = q2 * q2;                                                 \
            p[m][s][e] = q4 * q4;                                               \
            r[m][s][e] = t;                                                     \
        }                                                                       \
    }

    // stage group g_ (3 steps, 24 KB cg-slice) into Blds[b_]; per wave: 3 dmas
#define STAGE(g_, b_)                                                           \
    {                                                                           \
        _Pragma("unroll") for (int q = 0; q < GSTEP; ++q) {                     \
            int st  = (g_) * GSTEP + q;                                         \
            const ushort* sp = wc + (size_t)st * STEP_ELEMS + cg * 4096         \
                               + wave * 512 + lane * 8;                         \
            ushort* dp = &Blds[b_][q * 4096 + wave * 512 + lane * 8];           \
            __builtin_amdgcn_global_load_lds(                                   \
                (const __attribute__((address_space(1))) void*)sp,              \
                (__attribute__((address_space(3))) void*)dp, 16, 0, 0);         \
        }                                                                       \
    }

    LOAD_X(0);
    STAGE(0, 0);

#pragma unroll 1
    for (int g = 0; g < NGROUP; ++g) {
        __syncthreads();                       // group g resident; prev buf free
        if (g + 1 < NGROUP) STAGE(g + 1, (g + 1) & 1);

        const int ic = g / 3;
        const int gm = g - ic * 3;             // g % 3
        if (gm == 0) SETUP_BASIS();            // consume xb for chunk ic
        if (gm == 1 && ic + 1 < 4) LOAD_X(ic + 1);   // 1.5 groups of cover

        const ushort* Bp = Blds[g & 1];
#pragma unroll
        for (int q = 0; q < GSTEP; ++q) {
            const int kc = gm * 3 + q;         // step index within chunk, 0..8
            short8 bfr[2][4];
#pragma unroll
            for (int s = 0; s < 2; ++s)
#pragma unroll
                for (int n = 0; n < 4; ++n)
                    bfr[s][n] = *(const short8*)&Bp[q * 4096 + (n * 2 + s) * 512 + lane * 8];

#pragma unroll
            for (int s = 0; s < 2; ++s)
#pragma unroll
                for (int m = 0; m < 2; ++m) {
                    union { short8 v; __hip_bfloat162 h2[4]; } pk;
#pragma unroll
                    for (int e = 0; e < 8; e += 2)
                        pk.h2[e >> 1] = __float22bfloat162_rn(
                            make_float2(p[m][s][e], p[m][s][e + 1]));
#pragma unroll
                    for (int n = 0; n < 4; ++n)
                        acc[m][n] = __builtin_amdgcn_mfma_f32_16x16x32_bf16(
                            pk.v, bfr[s][n], acc[m][n], 0, 0, 0);
                    if (kc < NK - 1)
#pragma unroll
                        for (int e = 0; e < 8; ++e) p[m][s][e] *= r[m][s][e];
                }
        }
    }

    // ---- epilogue: C/D layout col=lane&15, row=(lane>>4)*4+reg ----
#pragma unroll
    for (int m = 0; m < 2; ++m) {
#pragma unroll
        for (int n = 0; n < 4; ++n) {
            int col   = cg * 64 + n * 16 + (lane & 15);
            int rbase = rb + m * 16 + (lane >> 4) * 4;
#pragma unroll
            for (int reg = 0; reg < 4; ++reg) {
                out[(size_t)(rbase + reg) * ODIM + col] = acc[m][n][reg];
            }
        }
    }
#undef LOAD_X
#undef SETUP_BASIS
#undef STAGE
}

extern "C" void kernel_launch(void* const* d_in, const int* in_sizes, int n_in,
                              void* d_out, int out_size, void* d_ws, size_t ws_size,
                              hipStream_t stream) {
    const float* x       = (const float*)d_in[0];   // [B, I]
    const float* weights = (const float*)d_in[1];   // [O, I]
    const float* coeffs  = (const float*)d_in[2];   // [O, I, 9]
    float* out = (float*)d_out;                     // [B, O]
    ushort* wc = (ushort*)d_ws;                     // 36 * 32 KB = 1.13 MB

    prep_wc3<<<ODIM, 256, 0, stream>>>(weights, coeffs, wc);
    bern_gemm<<<256, 512, 0, stream>>>(x, wc, out);
}